// Round 1
// baseline (1045.263 us; speedup 1.0000x reference)
//
#include <hip/hip_runtime.h>

#define T_TOT 262144
#define S_DIM 512
#define A_DIM 64
#define GAMMA 0.99f
#define GL 0.9702f    /* gamma*lam in f32, matching f64->f32 rounding of 0.99*0.98 */
#define CLIP_LO 0.8f
#define CLIP_HI 1.2f
#define ENT_COEF 0.01f

typedef __bf16 bf16_t;
typedef bf16_t bf16x4 __attribute__((ext_vector_type(4)));
typedef bf16_t bf16x8 __attribute__((ext_vector_type(8)));
typedef float f32x4 __attribute__((ext_vector_type(4)));

#define LDA 520   /* bf16 elems per LDS row: 512 + 8 pad -> bank-balanced */
#define LDL 68    /* f32 elems per logits row: 64 + 4 pad */

// ---------------------------------------------------------------------------
// K1: fused  critic-dots + actor GEMM (MFMA bf16) + log-softmax epilogue.
// Writes delta[t], ratio[t]; accumulates entropy sum into acc[0].
// ---------------------------------------------------------------------------
__global__ void ppo_main(const float* __restrict__ states,
                         const float* __restrict__ next_states,
                         const float* __restrict__ rewards,
                         const int*   __restrict__ dones,
                         const int*   __restrict__ actions,
                         const float* __restrict__ log_probs,
                         const float* __restrict__ actor_w,
                         const float* __restrict__ actor_b,
                         const float* __restrict__ critic_w,
                         const float* __restrict__ critic_b,
                         float* __restrict__ d_delta,
                         float* __restrict__ d_ratio,
                         float* __restrict__ acc) {
  __shared__ bf16_t sA[16 * LDA];
  __shared__ float  sLogits[16 * LDL];
  __shared__ float  sCW[S_DIM];
  __shared__ float  sB[A_DIM];
  __shared__ float  sV[16], sNV[16];

  const int t    = threadIdx.x;
  const int wave = t >> 6;
  const int lane = t & 63;
  const int q    = lane >> 4;   // quad 0..3
  const int r    = lane & 15;   // 0..15
  const int srow = t >> 4;      // staging row 0..15
  const int ssub = t & 15;      // 0..15 (16 threads per row)

  // one-time preloads
  const float cb = critic_b[0];
  for (int i = t; i < S_DIM; i += 256) sCW[i] = critic_w[i];
  if (t < A_DIM) sB[t] = actor_b[t];

  // register-resident B fragments: wave w owns columns [16w, 16w+16)
  // B-layout for mfma_f32_16x16x32_bf16: lane holds B[k = q*8+j][n = lane&15]
  const int colB = (wave << 4) + r;
  bf16x8 bfrag[16];
#pragma unroll
  for (int kt = 0; kt < 16; ++kt) {
    bf16x8 f;
#pragma unroll
    for (int j = 0; j < 8; ++j)
      f[j] = (bf16_t)actor_w[(kt * 32 + q * 8 + j) * A_DIM + colB];
    bfrag[kt] = f;
  }
  __syncthreads();

  float entloc = 0.f;

  for (int iter = blockIdx.x; iter < (T_TOT / 16); iter += gridDim.x) {
    const int row0 = iter * 16;

    // ---- stage 16 rows: fp32 loads, critic dots, bf16 -> LDS ----
    const float4* sp = (const float4*)(states      + (size_t)(row0 + srow) * S_DIM);
    const float4* np = (const float4*)(next_states + (size_t)(row0 + srow) * S_DIM);
    float vp = 0.f, nvp = 0.f;
#pragma unroll
    for (int i = 0; i < 8; ++i) {
      const int k4 = ssub + (i << 4);          // float4 index within row
      float4 s4 = sp[k4];
      float4 n4 = np[k4];
      float4 w4 = *(const float4*)(&sCW[k4 << 2]);
      vp  += s4.x * w4.x + s4.y * w4.y + s4.z * w4.z + s4.w * w4.w;
      nvp += n4.x * w4.x + n4.y * w4.y + n4.z * w4.z + n4.w * w4.w;
      bf16x4 b4;
      b4[0] = (bf16_t)s4.x; b4[1] = (bf16_t)s4.y;
      b4[2] = (bf16_t)s4.z; b4[3] = (bf16_t)s4.w;
      *(bf16x4*)(&sA[srow * LDA + (k4 << 2)]) = b4;
    }
#pragma unroll
    for (int off = 8; off > 0; off >>= 1) {
      vp  += __shfl_down(vp,  off, 16);
      nvp += __shfl_down(nvp, off, 16);
    }
    if (ssub == 0) { sV[srow] = vp + cb; sNV[srow] = nvp + cb; }
    __syncthreads();

    // ---- MFMA: 16 rows x 16 cols per wave over K=512 ----
    // A-layout: lane holds A[m = lane&15][k = q*8+j]
    f32x4 accv = {0.f, 0.f, 0.f, 0.f};
#pragma unroll
    for (int kt = 0; kt < 16; ++kt) {
      bf16x8 a = *(const bf16x8*)(&sA[r * LDA + kt * 32 + q * 8]);
      accv = __builtin_amdgcn_mfma_f32_16x16x32_bf16(a, bfrag[kt], accv, 0, 0, 0);
    }
    // C/D layout: col = lane&15, row = q*4 + reg
#pragma unroll
    for (int i = 0; i < 4; ++i)
      sLogits[(q * 4 + i) * LDL + (wave << 4) + r] = accv[i];
    __syncthreads();

    // ---- softmax epilogue: 16 threads per row, 4 cols each ----
    float4 l4 = *(const float4*)(&sLogits[srow * LDL + (ssub << 2)]);
    float4 b4 = *(const float4*)(&sB[ssub << 2]);
    l4.x += b4.x; l4.y += b4.y; l4.z += b4.z; l4.w += b4.w;
    float mx = fmaxf(fmaxf(l4.x, l4.y), fmaxf(l4.z, l4.w));
#pragma unroll
    for (int off = 8; off > 0; off >>= 1) mx = fmaxf(mx, __shfl_xor(mx, off, 16));
    const float e0 = __expf(l4.x - mx), e1 = __expf(l4.y - mx);
    const float e2 = __expf(l4.z - mx), e3 = __expf(l4.w - mx);
    float zs = e0 + e1 + e2 + e3;
#pragma unroll
    for (int off = 8; off > 0; off >>= 1) zs += __shfl_xor(zs, off, 16);
    const float lz = __logf(zs);
    const float lp0 = l4.x - mx - lz, lp1 = l4.y - mx - lz;
    const float lp2 = l4.z - mx - lz, lp3 = l4.w - mx - lz;
    float pl = e0 * lp0 + e1 * lp1 + e2 * lp2 + e3 * lp3;
#pragma unroll
    for (int off = 8; off > 0; off >>= 1) pl += __shfl_xor(pl, off, 16);
    pl /= zs;                                  // sum_a p*logp for this row
    float4 lpv = make_float4(lp0, lp1, lp2, lp3);
    *(float4*)(&sLogits[srow * LDL + (ssub << 2)]) = lpv;  // same-wave readers below

    if (ssub == 0) {
      const int gt = row0 + srow;
      const float nd = 1.f - (float)dones[gt];
      const float delta = rewards[gt] + GAMMA * sNV[srow] * nd - sV[srow];
      const int a = actions[gt];
      const float nlp = sLogits[srow * LDL + a];
      const float ratio = __expf(nlp - log_probs[gt]);
      d_delta[gt] = delta;
      d_ratio[gt] = ratio;
      entloc -= pl;                            // entropy_row = -sum p*logp
    }
    __syncthreads();
  }
  if (ssub == 0) atomicAdd(&acc[0], entloc);
}

// ---------------------------------------------------------------------------
// GAE as parallel scan of affine maps f_t(x) = delta_t + c_t * x (reverse).
// Segment compose (left earlier in time): (a,b) o (a',b') = (a + b*a', b*b')
// ---------------------------------------------------------------------------
__global__ void gae_block_affine(const float* __restrict__ delta,
                                 const int* __restrict__ dones,
                                 float* __restrict__ blkA, float* __restrict__ blkB) {
  const int t = threadIdx.x;
  const int base = blockIdx.x * 1024 + t * 4;
  float a = 0.f, b = 1.f;
#pragma unroll
  for (int j = 3; j >= 0; --j) {
    const float c = GL * (1.f - (float)dones[base + j]);
    a = delta[base + j] + c * a;
    b = c * b;
  }
  __shared__ float sa[256], sb[256];
  sa[t] = a; sb[t] = b;
  __syncthreads();
  for (int s = 1; s < 256; s <<= 1) {
    if ((t & (2 * s - 1)) == 0) {
      const float ar = sa[t + s], br = sb[t + s];
      sa[t] = sa[t] + sb[t] * ar;
      sb[t] = sb[t] * br;
    }
    __syncthreads();
  }
  if (t == 0) { blkA[blockIdx.x] = sa[0]; blkB[blockIdx.x] = sb[0]; }
}

__global__ void gae_block_scan(const float* __restrict__ blkA,
                               const float* __restrict__ blkB,
                               float* __restrict__ blkIn) {
  const int t = threadIdx.x;  // 256
  __shared__ float sa[256], sb[256];
  sa[t] = blkA[t]; sb[t] = blkB[t];
  __syncthreads();
  for (int d = 1; d < 256; d <<= 1) {
    float na = sa[t], nb = sb[t];
    if (t + d < 256) { na = sa[t] + sb[t] * sa[t + d]; nb = sb[t] * sb[t + d]; }
    __syncthreads();
    sa[t] = na; sb[t] = nb;
    __syncthreads();
  }
  blkIn[t] = (t < 255) ? sa[t + 1] : 0.f;   // adv entering block t from the right
}

__global__ void gae_apply_loss(const float* __restrict__ delta,
                               const int* __restrict__ dones,
                               const float* __restrict__ ratio,
                               const float* __restrict__ blkIn,
                               float* __restrict__ acc) {
  const int t = threadIdx.x;
  const int base = blockIdx.x * 1024 + t * 4;
  float dl[4], cc[4];
#pragma unroll
  for (int j = 0; j < 4; ++j) {
    dl[j] = delta[base + j];
    cc[j] = GL * (1.f - (float)dones[base + j]);
  }
  float a = 0.f, b = 1.f;
#pragma unroll
  for (int j = 3; j >= 0; --j) { a = dl[j] + cc[j] * a; b = cc[j] * b; }

  __shared__ float sa[256], sb[256];
  sa[t] = a; sb[t] = b;
  __syncthreads();
  for (int d = 1; d < 256; d <<= 1) {
    float na = sa[t], nb = sb[t];
    if (t + d < 256) { na = sa[t] + sb[t] * sa[t + d]; nb = sb[t] * sb[t + d]; }
    __syncthreads();
    sa[t] = na; sb[t] = nb;
    __syncthreads();
  }
  float x = blkIn[blockIdx.x];
  if (t < 255) x = sa[t + 1] + sb[t + 1] * x;   // adv entering this thread's segment

  float msum = 0.f, a2 = 0.f;
#pragma unroll
  for (int j = 3; j >= 0; --j) {
    x = dl[j] + cc[j] * x;                      // adv[base+j]
    const float rt = ratio[base + j];
    const float s1 = rt * x;
    const float rc = fminf(fmaxf(rt, CLIP_LO), CLIP_HI);
    const float s2 = rc * x;
    msum += fminf(s1, s2);
    a2 += x * x;
  }
  // block reduce
#pragma unroll
  for (int off = 32; off > 0; off >>= 1) {
    msum += __shfl_down(msum, off, 64);
    a2   += __shfl_down(a2,   off, 64);
  }
  __shared__ float rm[4], ra[4];
  if ((t & 63) == 0) { rm[t >> 6] = msum; ra[t >> 6] = a2; }
  __syncthreads();
  if (t == 0) {
    atomicAdd(&acc[1], rm[0] + rm[1] + rm[2] + rm[3]);
    atomicAdd(&acc[2], ra[0] + ra[1] + ra[2] + ra[3]);
  }
}

__global__ void ppo_finalize(const float* __restrict__ acc, float* __restrict__ out) {
  if (threadIdx.x == 0) {
    const float invT = 1.0f / (float)T_TOT;
    out[0] = -(acc[1] * invT) - ENT_COEF * (acc[0] * invT);
    out[1] = acc[2] * invT;
  }
}

extern "C" void kernel_launch(void* const* d_in, const int* in_sizes, int n_in,
                              void* d_out, int out_size, void* d_ws, size_t ws_size,
                              hipStream_t stream) {
  const float* states      = (const float*)d_in[0];
  const float* next_states = (const float*)d_in[1];
  const float* rewards     = (const float*)d_in[2];
  const int*   dones       = (const int*)d_in[3];
  const int*   actions     = (const int*)d_in[4];
  const float* log_probs   = (const float*)d_in[5];
  const float* actor_w     = (const float*)d_in[6];
  const float* actor_b     = (const float*)d_in[7];
  const float* critic_w    = (const float*)d_in[8];
  const float* critic_b    = (const float*)d_in[9];
  float* out = (float*)d_out;

  char* ws = (char*)d_ws;
  float* delta = (float*)ws;                       // T floats
  float* ratio = (float*)(ws + (size_t)T_TOT * 4); // T floats
  float* blkA  = (float*)(ws + (size_t)2 * T_TOT * 4);
  float* blkB  = blkA + 256;
  float* blkIn = blkB + 256;
  float* acc   = blkIn + 256;                      // [0]=ent, [1]=msum, [2]=adv2

  hipMemsetAsync(acc, 0, 3 * sizeof(float), stream);

  ppo_main<<<2048, 256, 0, stream>>>(states, next_states, rewards, dones, actions,
                                     log_probs, actor_w, actor_b, critic_w, critic_b,
                                     delta, ratio, acc);
  gae_block_affine<<<256, 256, 0, stream>>>(delta, dones, blkA, blkB);
  gae_block_scan<<<1, 256, 0, stream>>>(blkA, blkB, blkIn);
  gae_apply_loss<<<256, 256, 0, stream>>>(delta, dones, ratio, blkIn, acc);
  ppo_finalize<<<1, 64, 0, stream>>>(acc, out);
}